// Round 4
// baseline (118.995 us; speedup 1.0000x reference)
//
#include <hip/hip_runtime.h>

// LengthRegulator, fully fused single kernel, nontemporal output stream.
// x (B,DIM,T) f32, duration (B,T) i32 -> out (B,DIM,DMAX) f32, mel_len (B,) as f32
#define B_SZ   16
#define DIM_SZ 384
#define T_SZ   512
#define DMAX   4096
#define DC     8      // dims per block (384/8 = 48 z-blocks)
#define FC     2048   // frames per block (4096/2048 = 2 x-blocks)

// Native clang vector type: __builtin_nontemporal_* requires it (HIP float4 is a struct).
typedef float f32x4 __attribute__((ext_vector_type(4)));

// grid: (DMAX/FC, B, DIM/DC), block 256.
// Wave 0 re-derives the duration scan in registers (L2-resident, cheap) and
// scatters the inverse searchsorted index into LDS. Output stores are
// nontemporal (write-once, no reuse -> bypass L2 allocation). Pad blocks
// (f0 >= mel) stream zeros without staging x.
__global__ __launch_bounds__(256) void lr_fused_kernel(const float* __restrict__ x,
                                                       const int* __restrict__ duration,
                                                       float* __restrict__ out,
                                                       float* __restrict__ mel_out) {
    __shared__ float s_x[DC * T_SZ];        // 16 KB
    __shared__ unsigned short s_idx[FC];    // 4 KB
    __shared__ int s_mel;
    const int tid = threadIdx.x;
    const int b   = blockIdx.y;
    const int d0  = blockIdx.z * DC;
    const int f0  = blockIdx.x * FC;

    const f32x4* __restrict__ xsrc = (const f32x4*)(x + ((size_t)b * DIM_SZ + d0) * T_SZ);
    f32x4* s_x4 = (f32x4*)s_x;
    const bool eager = (f0 == 0);   // f0==0 blocks almost surely do real work
    if (eager) {
#pragma unroll
        for (int i = 0; i < (DC * T_SZ / 4) / 256; ++i)   // 4 coalesced float4 iters
            s_x4[i * 256 + tid] = __builtin_nontemporal_load(&xsrc[i * 256 + tid]);
    }

    if (tid < 64) {
        // register prefix + shfl wave scan of this batch row's durations
        const int l = tid;
        const int4* __restrict__ src = (const int4*)(duration + b * T_SZ);
        const int4 a = src[l * 2];
        const int4 c = src[l * 2 + 1];
        int p[8];
        p[0] = a.x;        p[1] = p[0] + a.y; p[2] = p[1] + a.z; p[3] = p[2] + a.w;
        p[4] = p[3] + c.x; p[5] = p[4] + c.y; p[6] = p[5] + c.z; p[7] = p[6] + c.w;
        int s = p[7];
#pragma unroll
        for (int off = 1; off < 64; off <<= 1) {
            const int v = __shfl_up(s, off);
            if (l >= off) s += v;
        }
        const int excl   = s - p[7];
        const int rowsum = __shfl(s, 63);
        if (rowsum == 0) {
            // reference: row_sum==0 -> duration := ones -> idx[f] = f, mel = T
            if (f0 == 0) {
                const int t0 = l * 8;
                ushort4* dst = (ushort4*)(s_idx + t0);
                dst[0] = make_ushort4((unsigned short)(t0 + 0), (unsigned short)(t0 + 1),
                                      (unsigned short)(t0 + 2), (unsigned short)(t0 + 3));
                dst[1] = make_ushort4((unsigned short)(t0 + 4), (unsigned short)(t0 + 5),
                                      (unsigned short)(t0 + 6), (unsigned short)(t0 + 7));
            }
            if (l == 63) {
                s_mel = T_SZ;
                if (blockIdx.x == 0 && blockIdx.z == 0) mel_out[b] = (float)T_SZ;
            }
        } else {
            // frames [excl + p[k-1], excl + p[k]) belong to timestep t = l*8+k;
            // scatter only the slice this block consumes: [f0, f0+FC)
            int start = excl;
#pragma unroll
            for (int k = 0; k < 8; ++k) {
                const unsigned short t = (unsigned short)(l * 8 + k);
                const int e  = excl + p[k];
                const int lo = start < f0 ? f0 : start;
                const int hi = e > f0 + FC ? f0 + FC : e;
                for (int f = lo; f < hi; ++f) s_idx[f - f0] = t;
                start = e;
            }
            if (l == 63) {
                s_mel = rowsum;
                if (blockIdx.x == 0 && blockIdx.z == 0) mel_out[b] = (float)rowsum;
            }
        }
    }
    __syncthreads();

    const int mel = s_mel;
    f32x4* __restrict__ outp = (f32x4*)(out + (size_t)b * DIM_SZ * DMAX);

    if (f0 >= mel) {
        // whole block is pad: nontemporal zero-stream only
        const f32x4 z = (f32x4)(0.f);
#pragma unroll
        for (int g = 0; g < FC / 1024; ++g) {
            const int f4 = ((f0 + g * 1024) >> 2) + tid;
#pragma unroll
            for (int dd = 0; dd < DC; ++dd)
                __builtin_nontemporal_store(z, &outp[(size_t)(d0 + dd) * (DMAX / 4) + f4]);
        }
        return;
    }
    if (!eager) {
        // f0 > 0 but mel > f0 — statistically never, kept for correctness
#pragma unroll
        for (int i = 0; i < (DC * T_SZ / 4) / 256; ++i)
            s_x4[i * 256 + tid] = __builtin_nontemporal_load(&xsrc[i * 256 + tid]);
        __syncthreads();
    }

#pragma unroll
    for (int g = 0; g < FC / 1024; ++g) {
        const int f  = f0 + g * 1024 + tid * 4;
        const int f4 = f >> 2;   // global float4 index along frame axis
        if (f >= mel) {
            const f32x4 z = (f32x4)(0.f);
#pragma unroll
            for (int dd = 0; dd < DC; ++dd)
                __builtin_nontemporal_store(z, &outp[(size_t)(d0 + dd) * (DMAX / 4) + f4]);
        } else {
            const ushort4 i4 = ((const ushort4*)s_idx)[g * 256 + tid];
            // &511 clamps garbage in the never-scattered tail (f >= mel lanes
            // are masked by valid[] anyway) so LDS access stays in-bounds.
            int idx[4] = { i4.x & (T_SZ - 1), i4.y & (T_SZ - 1),
                           i4.z & (T_SZ - 1), i4.w & (T_SZ - 1) };
            bool valid[4];
#pragma unroll
            for (int j = 0; j < 4; ++j) valid[j] = (f + j < mel);
#pragma unroll
            for (int dd = 0; dd < DC; ++dd) {
                const float* __restrict__ xr = s_x + dd * T_SZ;
                f32x4 v;
                v.x = valid[0] ? xr[idx[0]] : 0.0f;
                v.y = valid[1] ? xr[idx[1]] : 0.0f;
                v.z = valid[2] ? xr[idx[2]] : 0.0f;
                v.w = valid[3] ? xr[idx[3]] : 0.0f;
                __builtin_nontemporal_store(v, &outp[(size_t)(d0 + dd) * (DMAX / 4) + f4]);
            }
        }
    }
}

extern "C" void kernel_launch(void* const* d_in, const int* in_sizes, int n_in,
                              void* d_out, int out_size, void* d_ws, size_t ws_size,
                              hipStream_t stream) {
    const float* x        = (const float*)d_in[0];
    const int*   duration = (const int*)d_in[1];
    // d_in[2] is d_max == 4096, static for this problem instance.

    float* out     = (float*)d_out;
    float* mel_out = out + (size_t)B_SZ * DIM_SZ * DMAX;
    (void)d_ws; (void)ws_size;   // workspace not needed

    dim3 grid(DMAX / FC, B_SZ, DIM_SZ / DC);
    lr_fused_kernel<<<grid, 256, 0, stream>>>(x, duration, out, mel_out);
}

// Round 5
// 114.829 us; speedup vs baseline: 1.0363x; 1.0363x over previous
//
#include <hip/hip_runtime.h>

// LengthRegulator, fully fused single kernel.
// x (B,DIM,T) f32, duration (B,T) i32 -> out (B,DIM,DMAX) f32, mel_len (B,) as f32
#define B_SZ   16
#define DIM_SZ 384
#define T_SZ   512
#define DMAX   4096
#define DC     8      // dims per block (384/8 = 48 z-blocks)
#define FC     2048   // frames per block (4096/2048 = 2 x-blocks)

// grid: (DMAX/FC, B, DIM/DC), block 256.
// Wave 0 of every block redoes the (cheap, L2-resident) duration scan in
// registers and scatters the inverse searchsorted index into LDS; no scan
// kernel, no workspace round-trip, no second launch. Zero-pad blocks
// (f0 >= mel, ~always true for f0=2048 since E[mel]~1792) do zero-stores only.
// NT stores were tried (R4) and measured neutral-to-worse — plain stores kept.
// LDS: 16KB x-slice + 4KB idx + 4B mel ~= 20.5KB -> 7 blocks/CU >= 6 needed.
__global__ __launch_bounds__(256) void lr_fused_kernel(const float* __restrict__ x,
                                                       const int* __restrict__ duration,
                                                       float* __restrict__ out,
                                                       float* __restrict__ mel_out) {
    __shared__ float s_x[DC * T_SZ];        // 16 KB
    __shared__ unsigned short s_idx[FC];    // 4 KB
    __shared__ int s_mel;
    const int tid = threadIdx.x;
    const int b   = blockIdx.y;
    const int d0  = blockIdx.z * DC;
    const int f0  = blockIdx.x * FC;

    const float4* __restrict__ xsrc = (const float4*)(x + ((size_t)b * DIM_SZ + d0) * T_SZ);
    float4* s_x4 = (float4*)s_x;
    const bool eager = (f0 == 0);   // f0==0 blocks almost surely do real work
    if (eager) {
#pragma unroll
        for (int i = 0; i < (DC * T_SZ / 4) / 256; ++i)   // 4 coalesced float4 iters
            s_x4[i * 256 + tid] = xsrc[i * 256 + tid];
    }

    if (tid < 64) {
        // register prefix + shfl wave scan of this batch row's durations
        const int l = tid;
        const int4* __restrict__ src = (const int4*)(duration + b * T_SZ);
        const int4 a = src[l * 2];
        const int4 c = src[l * 2 + 1];
        int p[8];
        p[0] = a.x;        p[1] = p[0] + a.y; p[2] = p[1] + a.z; p[3] = p[2] + a.w;
        p[4] = p[3] + c.x; p[5] = p[4] + c.y; p[6] = p[5] + c.z; p[7] = p[6] + c.w;
        int s = p[7];
#pragma unroll
        for (int off = 1; off < 64; off <<= 1) {
            const int v = __shfl_up(s, off);
            if (l >= off) s += v;
        }
        const int excl   = s - p[7];
        const int rowsum = __shfl(s, 63);
        if (rowsum == 0) {
            // reference: row_sum==0 -> duration := ones -> idx[f] = f, mel = T
            if (f0 == 0) {
                const int t0 = l * 8;
                ushort4* dst = (ushort4*)(s_idx + t0);
                dst[0] = make_ushort4((unsigned short)(t0 + 0), (unsigned short)(t0 + 1),
                                      (unsigned short)(t0 + 2), (unsigned short)(t0 + 3));
                dst[1] = make_ushort4((unsigned short)(t0 + 4), (unsigned short)(t0 + 5),
                                      (unsigned short)(t0 + 6), (unsigned short)(t0 + 7));
            }
            if (l == 63) {
                s_mel = T_SZ;
                if (blockIdx.x == 0 && blockIdx.z == 0) mel_out[b] = (float)T_SZ;
            }
        } else {
            // frames [excl + p[k-1], excl + p[k]) belong to timestep t = l*8+k;
            // scatter only the slice this block consumes: [f0, f0+FC)
            int start = excl;
#pragma unroll
            for (int k = 0; k < 8; ++k) {
                const unsigned short t = (unsigned short)(l * 8 + k);
                const int e  = excl + p[k];
                const int lo = start < f0 ? f0 : start;
                const int hi = e > f0 + FC ? f0 + FC : e;
                for (int f = lo; f < hi; ++f) s_idx[f - f0] = t;
                start = e;
            }
            if (l == 63) {
                s_mel = rowsum;
                if (blockIdx.x == 0 && blockIdx.z == 0) mel_out[b] = (float)rowsum;
            }
        }
    }
    __syncthreads();

    const int mel = s_mel;
    float4* __restrict__ outp = (float4*)(out + (size_t)b * DIM_SZ * DMAX);

    if (f0 >= mel) {
        // whole block is pad: zero-stores only
        const float4 z = make_float4(0.f, 0.f, 0.f, 0.f);
#pragma unroll
        for (int g = 0; g < FC / 1024; ++g) {
            const int f4 = ((f0 + g * 1024) >> 2) + tid;
#pragma unroll
            for (int dd = 0; dd < DC; ++dd)
                outp[(size_t)(d0 + dd) * (DMAX / 4) + f4] = z;
        }
        return;
    }
    if (!eager) {
        // f0 > 0 but mel > f0 — statistically never, kept for correctness
#pragma unroll
        for (int i = 0; i < (DC * T_SZ / 4) / 256; ++i)
            s_x4[i * 256 + tid] = xsrc[i * 256 + tid];
        __syncthreads();
    }

#pragma unroll
    for (int g = 0; g < FC / 1024; ++g) {
        const int f  = f0 + g * 1024 + tid * 4;
        const int f4 = f >> 2;   // global float4 index along frame axis
        if (f >= mel) {
            const float4 z = make_float4(0.f, 0.f, 0.f, 0.f);
#pragma unroll
            for (int dd = 0; dd < DC; ++dd)
                outp[(size_t)(d0 + dd) * (DMAX / 4) + f4] = z;
        } else {
            const ushort4 i4 = ((const ushort4*)s_idx)[g * 256 + tid];
            // &511 clamps garbage in the never-scattered tail (f >= mel lanes
            // are masked by valid[] anyway) so LDS access stays in-bounds.
            int idx[4] = { i4.x & (T_SZ - 1), i4.y & (T_SZ - 1),
                           i4.z & (T_SZ - 1), i4.w & (T_SZ - 1) };
            bool valid[4];
#pragma unroll
            for (int j = 0; j < 4; ++j) valid[j] = (f + j < mel);
#pragma unroll
            for (int dd = 0; dd < DC; ++dd) {
                const float* __restrict__ xr = s_x + dd * T_SZ;
                float4 v;
                v.x = valid[0] ? xr[idx[0]] : 0.0f;
                v.y = valid[1] ? xr[idx[1]] : 0.0f;
                v.z = valid[2] ? xr[idx[2]] : 0.0f;
                v.w = valid[3] ? xr[idx[3]] : 0.0f;
                outp[(size_t)(d0 + dd) * (DMAX / 4) + f4] = v;
            }
        }
    }
}

extern "C" void kernel_launch(void* const* d_in, const int* in_sizes, int n_in,
                              void* d_out, int out_size, void* d_ws, size_t ws_size,
                              hipStream_t stream) {
    const float* x        = (const float*)d_in[0];
    const int*   duration = (const int*)d_in[1];
    // d_in[2] is d_max == 4096, static for this problem instance.

    float* out     = (float*)d_out;
    float* mel_out = out + (size_t)B_SZ * DIM_SZ * DMAX;
    (void)d_ws; (void)ws_size;   // workspace not needed

    dim3 grid(DMAX / FC, B_SZ, DIM_SZ / DC);
    lr_fused_kernel<<<grid, 256, 0, stream>>>(x, duration, out, mel_out);
}